// Round 1
// 205.716 us; speedup vs baseline: 1.0059x; 1.0059x over previous
//
#include <hip/hip_runtime.h>

#define B_ 16
#define L_ 2048
#define D_ 1024
#define S_ 32

// ---------------- Kernel B: fused lengths + span-mean + classifier head ----------------
// One block per (b,s) span; 1024 threads = 4 row-slots x 256 dim-chunks (float4).
// Changes vs previous version (theory: latency-hiding + loop VALU):
//  - sum-first: hot loop only accumulates float4 sums (4 adds/16B); the 4x3
//    weight projection happens ONCE after the loop (frees 12 regs from the loop).
//  - unroll x4: 4 independent float4 loads in flight per wave.
//  - __launch_bounds__(1024, 8): 8 waves/EU -> 2 blocks/CU guaranteed (VGPR<=64).
//  - epilogue parallelized onto wave 0 (segmented shuffle reduce; lanes 0..2
//    each produce one logit, embedding dot products load in parallel).
__global__ __launch_bounds__(1024, 8) void span_logits_kernel(
        const float* __restrict__ enc,
        const int* __restrict__ mask,
        const int* __restrict__ head,
        const int* __restrict__ tail,
        const float* __restrict__ wemb,
        const float* __restrict__ lemb,
        const float* __restrict__ cls_w,
        const float* __restrict__ cls_b,
        float* __restrict__ out) {
    const int bs = blockIdx.x;            // 0..511
    const int b  = bs / S_;
    const int t  = threadIdx.x;           // 0..1023
    const int h  = head[bs];
    const int tl = tail[bs];
    int lo = h + 1; if (lo < 0) lo = 0;
    int hi = tl;    if (hi > L_) hi = L_;
    const int nrow = hi - lo;

    const int rg = t >> 8;                // row-slot 0..3
    const int dc = (t & 255) * 4;         // dim chunk base (4 fp32 = 16 B)

    // mask partial sum (2 ints per thread, 8B coalesced; L2-hot)
    const int2 mk = reinterpret_cast<const int2*>(mask + b * L_)[t];

    // --- hot loop: pure float4 accumulation, 4 loads in flight ---
    const float* base = enc + (size_t)b * (L_ * D_) + dc;
    float4 s0 = {0.f, 0.f, 0.f, 0.f};
    float4 s1 = s0, s2 = s0, s3 = s0;
    int l = lo + rg;
    for (; l + 12 < hi; l += 16) {
        const float4 u0 = *reinterpret_cast<const float4*>(base + (size_t)(l     ) * D_);
        const float4 u1 = *reinterpret_cast<const float4*>(base + (size_t)(l +  4) * D_);
        const float4 u2 = *reinterpret_cast<const float4*>(base + (size_t)(l +  8) * D_);
        const float4 u3 = *reinterpret_cast<const float4*>(base + (size_t)(l + 12) * D_);
        s0.x += u0.x; s0.y += u0.y; s0.z += u0.z; s0.w += u0.w;
        s1.x += u1.x; s1.y += u1.y; s1.z += u1.z; s1.w += u1.w;
        s2.x += u2.x; s2.y += u2.y; s2.z += u2.z; s2.w += u2.w;
        s3.x += u3.x; s3.y += u3.y; s3.z += u3.z; s3.w += u3.w;
    }
    for (; l < hi; l += 4) {
        const float4 u = *reinterpret_cast<const float4*>(base + (size_t)l * D_);
        s0.x += u.x; s0.y += u.y; s0.z += u.z; s0.w += u.w;
    }
    const float sx = (s0.x + s1.x) + (s2.x + s3.x);
    const float sy = (s0.y + s1.y) + (s2.y + s3.y);
    const float sz = (s0.z + s1.z) + (s2.z + s3.z);
    const float sw = (s0.w + s1.w) + (s2.w + s3.w);

    // weight projection once, after the loop (loads are L2-hot)
    const float w00 = cls_w[(dc + 0) * 3 + 0], w01 = cls_w[(dc + 0) * 3 + 1], w02 = cls_w[(dc + 0) * 3 + 2];
    const float w10 = cls_w[(dc + 1) * 3 + 0], w11 = cls_w[(dc + 1) * 3 + 1], w12 = cls_w[(dc + 1) * 3 + 2];
    const float w20 = cls_w[(dc + 2) * 3 + 0], w21 = cls_w[(dc + 2) * 3 + 1], w22 = cls_w[(dc + 2) * 3 + 2];
    const float w30 = cls_w[(dc + 3) * 3 + 0], w31 = cls_w[(dc + 3) * 3 + 1], w32 = cls_w[(dc + 3) * 3 + 2];
    float a0 = fmaf(sx, w00, fmaf(sy, w10, fmaf(sz, w20, sw * w30)));
    float a1 = fmaf(sx, w01, fmaf(sy, w11, fmaf(sz, w21, sw * w31)));
    float a2 = fmaf(sx, w02, fmaf(sy, w12, fmaf(sz, w22, sw * w32)));
    float fm = (float)(mk.x + mk.y);

    // wave-level reduction of 3 accumulators + mask sum
#pragma unroll
    for (int off = 32; off > 0; off >>= 1) {
        a0 += __shfl_down(a0, off, 64);
        a1 += __shfl_down(a1, off, 64);
        a2 += __shfl_down(a2, off, 64);
        fm += __shfl_down(fm, off, 64);
    }
    __shared__ float sred[64];
    const int wv = t >> 6;                // wave id 0..15
    if ((t & 63) == 0) {
        sred[wv]      = a0;
        sred[16 + wv] = a1;
        sred[32 + wv] = a2;
        sred[48 + wv] = fm;
    }
    __syncthreads();

    // wave 0: segmented reduce (16-lane groups), lanes 0..2 finish one logit each
    if (t < 64) {
        float v = sred[t];
        v += __shfl_down(v, 8, 16);
        v += __shfl_down(v, 4, 16);
        v += __shfl_down(v, 2, 16);
        v += __shfl_down(v, 1, 16);
        // heads now at lanes 0 (a0), 16 (a1), 32 (a2), 48 (len)
        const float flen = __shfl(v, 48, 64);
        const float rsel = __shfl(v, (t < 3 ? t : 0) << 4, 64);
        if (t < 3) {
            float cnt = (float)(nrow > 0 ? nrow : 1);
            float r = rsel / cnt;

            int wb = (tl - h) / 16;       // WIDTH_BUCKET = 16
            if (wb < 0) wb = 0;
            if (wb > 63) wb = 63;
            int lb = (int)flen / 32;      // LEN_BUCKET = 32
            if (lb < 0) lb = 0;
            if (lb > 63) lb = 63;
            const float* we = wemb + wb * 8;
            const float* le = lemb + lb * 8;
#pragma unroll
            for (int j = 0; j < 8; ++j) {
                r += we[j] * cls_w[(D_ + j) * 3 + t] + le[j] * cls_w[(D_ + 8 + j) * 3 + t];
            }
            r += cls_b[t];
            out[bs * 3 + t] = r;
        }
    }
}

// ---------------- Kernel C: cross-entropy over 512 spans ----------------
__global__ __launch_bounds__(512) void ce_kernel(const float* __restrict__ logits,
                                                 const int* __restrict__ labels,
                                                 float* __restrict__ out) {
    const int i = threadIdx.x;            // 0..511, one per (b,s)
    const int lab = labels[i];
    const float l0 = logits[i * 3 + 0];
    const float l1 = logits[i * 3 + 1];
    const float l2 = logits[i * 3 + 2];
    const float m  = fmaxf(l0, fmaxf(l1, l2));
    const float lse = m + logf(expf(l0 - m) + expf(l1 - m) + expf(l2 - m));
    int cl = lab < 0 ? 0 : (lab > 2 ? 2 : lab);
    const float pick = (cl == 0) ? l0 : ((cl == 1) ? l1 : l2);
    float nll = 0.f, val = 0.f;
    if (lab > -1) { nll = lse - pick; val = 1.f; }
#pragma unroll
    for (int off = 32; off > 0; off >>= 1) {
        nll += __shfl_down(nll, off, 64);
        val += __shfl_down(val, off, 64);
    }
    __shared__ float rn[8], rv[8];
    const int wv = i >> 6;
    if ((i & 63) == 0) { rn[wv] = nll; rv[wv] = val; }
    __syncthreads();
    if (i == 0) {
        float sn = 0.f, sv = 0.f;
#pragma unroll
        for (int k = 0; k < 8; ++k) { sn += rn[k]; sv += rv[k]; }
        out[B_ * S_ * 3] = sn / fmaxf(sv, 1.f);
    }
}

extern "C" void kernel_launch(void* const* d_in, const int* in_sizes, int n_in,
                              void* d_out, int out_size, void* d_ws, size_t ws_size,
                              hipStream_t stream) {
    const float* enc    = (const float*)d_in[0];
    const int*   mask   = (const int*)d_in[1];
    const int*   head   = (const int*)d_in[2];
    const int*   tail   = (const int*)d_in[3];
    const int*   labels = (const int*)d_in[4];
    const float* wemb   = (const float*)d_in[5];
    const float* lemb   = (const float*)d_in[6];
    const float* cls_w  = (const float*)d_in[7];
    const float* cls_b  = (const float*)d_in[8];
    float* out = (float*)d_out;           // [B*S*3 logits] + [1 ce_loss], fp32

    span_logits_kernel<<<B_ * S_, 1024, 0, stream>>>(enc, mask, head, tail, wemb, lemb,
                                                     cls_w, cls_b, out);
    ce_kernel<<<1, 512, 0, stream>>>(out, labels, out);
}